// Round 1
// baseline (130.676 us; speedup 1.0000x reference)
//
#include <hip/hip_runtime.h>
#include <hip/hip_bf16.h>

#define B_   2
#define L_   2048
#define C_   256
#define H_   8
#define DK_  32
#define HD_  256
#define RSQRT_DK 0.17677669529663687f  // 1/sqrt(32)

// ---------------------------------------------------------------------------
// Fused QKV projection GEMM.
// For proj p in {Q,K,V}: out_p = in_p (4096x256) @ W_p (256x256) + b_p,
// stored into (B,H,L,DK) layout in workspace.
// Grid: (64 m-tiles, 12) where blockIdx.y = proj*4 + n-tile. Tile 64x64, K-step 16.
// ---------------------------------------------------------------------------
__global__ __launch_bounds__(256) void gemm_qkv_kernel(
    const float* __restrict__ qx, const float* __restrict__ kx, const float* __restrict__ vx,
    const float* __restrict__ WQ, const float* __restrict__ bQ,
    const float* __restrict__ WK, const float* __restrict__ bK,
    const float* __restrict__ WV, const float* __restrict__ bV,
    float* __restrict__ ws)
{
    const int mt = blockIdx.x;
    const int yy = blockIdx.y;
    const int proj = yy >> 2;
    const int nt = yy & 3;
    const float* A    = proj == 0 ? qx : (proj == 1 ? kx : vx);
    const float* W    = proj == 0 ? WQ : (proj == 1 ? WK : WV);
    const float* bias = proj == 0 ? bQ : (proj == 1 ? bK : bV);
    float* out = ws + (size_t)proj * (B_ * H_ * L_ * DK_);

    __shared__ float As[16][64];
    __shared__ float Bs[16][64];

    const int tid = threadIdx.x;
    const int tx = tid & 15, ty = tid >> 4;
    const int m0 = mt * 64, n0 = nt * 64;

    const int arow = tid >> 2, akv = (tid & 3) * 4;   // A-stage: 64 rows x 16 k
    const int bkk = tid >> 4, bn4 = (tid & 15) * 4;   // B-stage: 16 k x 64 n

    float acc[4][4] = {};

    for (int k0 = 0; k0 < C_; k0 += 16) {
        float4 a4 = *reinterpret_cast<const float4*>(&A[(size_t)(m0 + arow) * C_ + k0 + akv]);
        float4 b4 = *reinterpret_cast<const float4*>(&W[(size_t)(k0 + bkk) * HD_ + n0 + bn4]);
        __syncthreads();
        As[akv + 0][arow] = a4.x;
        As[akv + 1][arow] = a4.y;
        As[akv + 2][arow] = a4.z;
        As[akv + 3][arow] = a4.w;
        *reinterpret_cast<float4*>(&Bs[bkk][bn4]) = b4;
        __syncthreads();
        #pragma unroll
        for (int kk = 0; kk < 16; ++kk) {
            float4 av = *reinterpret_cast<const float4*>(&As[kk][ty * 4]);
            float4 bv = *reinterpret_cast<const float4*>(&Bs[kk][tx * 4]);
            float ar[4] = {av.x, av.y, av.z, av.w};
            float br[4] = {bv.x, bv.y, bv.z, bv.w};
            #pragma unroll
            for (int i = 0; i < 4; ++i)
                #pragma unroll
                for (int j = 0; j < 4; ++j)
                    acc[i][j] += ar[i] * br[j];
        }
    }

    const int col = n0 + tx * 4;          // 0..255 within this projection
    const int h = col >> 5, d = col & 31; // col%32 is 4-aligned, never crosses head
    float4 bb = *reinterpret_cast<const float4*>(&bias[col]);
    #pragma unroll
    for (int i = 0; i < 4; ++i) {
        int mr = m0 + ty * 4 + i;
        int b = mr >> 11, l = mr & (L_ - 1);
        float4 o;
        o.x = acc[i][0] + bb.x;
        o.y = acc[i][1] + bb.y;
        o.z = acc[i][2] + bb.z;
        o.w = acc[i][3] + bb.w;
        *reinterpret_cast<float4*>(&out[((size_t)(b * H_ + h) * L_ + l) * DK_ + d]) = o;
    }
}

// ---------------------------------------------------------------------------
// Per-(b,h) column-sum of V: vsum[bh][d] = sum_l v[bh][l][d]
// ---------------------------------------------------------------------------
__global__ __launch_bounds__(256) void vsum_kernel(
    const float* __restrict__ v, float* __restrict__ vsum)
{
    const int bh = blockIdx.x;       // 16
    const int t = threadIdx.x;
    const int d = t & 31, g = t >> 5;
    const float* vb = v + (size_t)bh * L_ * DK_;
    float acc = 0.f;
    for (int l = g; l < L_; l += 8) acc += vb[l * DK_ + d];
    __shared__ float red[8][32];
    red[g][d] = acc;
    __syncthreads();
    if (g == 0) {
        float s = 0.f;
        #pragma unroll
        for (int gg = 0; gg < 8; ++gg) s += red[gg][d];
        vsum[bh * DK_ + d] = s;
    }
}

// ---------------------------------------------------------------------------
// Interior rows i in [1, L-2]: sparse softmax over S_i = {0, i-1, i, i+1, L-1}
// plus (L - |S_i|) zero-score entries. One 32-lane group per row, lane = dim d.
// ---------------------------------------------------------------------------
__global__ __launch_bounds__(256) void attn_interior_kernel(
    const float* __restrict__ q, const float* __restrict__ k,
    const float* __restrict__ v, const float* __restrict__ vsum,
    float* __restrict__ z)
{
    const int tid = threadIdx.x;
    const int d = tid & 31, rg = tid >> 5;
    const long gidx = (long)blockIdx.x * 8 + rg;       // global row-group index
    const int rowsPerBH = L_ - 2;                      // 2046
    const int bh = (int)(gidx / rowsPerBH);
    if (bh >= B_ * H_) return;
    const int i = 1 + (int)(gidx % rowsPerBH);

    const float* qb = q + (size_t)bh * L_ * DK_;
    const float* kb = k + (size_t)bh * L_ * DK_;
    const float* vb = v + (size_t)bh * L_ * DK_;

    const float qd = qb[i * DK_ + d];

    int cols[5] = {0, i - 1, i, i + 1, L_ - 1};
    bool valid[5] = {true, i != 1, true, i != L_ - 2, true};

    float s[5];
    #pragma unroll
    for (int jj = 0; jj < 5; ++jj) {
        float p = qd * kb[cols[jj] * DK_ + d];
        #pragma unroll
        for (int off = 16; off; off >>= 1) p += __shfl_xor(p, off, 32);
        s[jj] = p * RSQRT_DK;
    }

    float m = 0.f;  // zero-score filler entries participate in the row max
    int ns = 0;
    #pragma unroll
    for (int jj = 0; jj < 5; ++jj) {
        if (valid[jj]) { m = fmaxf(m, s[jj]); ns++; }
    }

    float e[5], sume = 0.f;
    #pragma unroll
    for (int jj = 0; jj < 5; ++jj) {
        e[jj] = valid[jj] ? __expf(s[jj] - m) : 0.f;
        sume += e[jj];
    }
    const float e0 = __expf(-m);
    const float Z = sume + (float)(L_ - ns) * e0;

    float zd = 0.f, vp = 0.f;
    #pragma unroll
    for (int jj = 0; jj < 5; ++jj) {
        float vd = vb[cols[jj] * DK_ + d];
        zd += e[jj] * vd;
        vp += valid[jj] ? vd : 0.f;
    }
    zd += e0 * (vsum[bh * DK_ + d] - vp);
    zd /= Z;

    const int b = bh >> 3, h = bh & 7;
    z[((size_t)(b * L_ + i)) * HD_ + h * DK_ + d] = zd;
}

// ---------------------------------------------------------------------------
// Global rows (i = 0 and i = L-1): fully dense row of real scores.
// One block per (b,h,row). 32 blocks total.
// ---------------------------------------------------------------------------
__global__ __launch_bounds__(256) void attn_global_kernel(
    const float* __restrict__ q, const float* __restrict__ k,
    const float* __restrict__ v, float* __restrict__ z)
{
    const int blk = blockIdx.x;          // 0..31
    const int bh = blk >> 1;
    const int r = (blk & 1) ? (L_ - 1) : 0;
    const float* qb = q + (size_t)bh * L_ * DK_;
    const float* kb = k + (size_t)bh * L_ * DK_;
    const float* vb = v + (size_t)bh * L_ * DK_;

    __shared__ float sc[L_];             // 8 KB scores/weights
    __shared__ float qs[DK_];
    __shared__ float wred[4], wsum[4];
    __shared__ float pz[8][32];

    const int tid = threadIdx.x;
    if (tid < DK_) qs[tid] = qb[r * DK_ + tid];
    __syncthreads();

    // phase 1: scores + local max
    float lmax = -1e30f;
    for (int j = tid; j < L_; j += 256) {
        const float4* kr = reinterpret_cast<const float4*>(&kb[(size_t)j * DK_]);
        float p = 0.f;
        #pragma unroll
        for (int u = 0; u < 8; ++u) {
            float4 kv = kr[u];
            p += qs[u * 4 + 0] * kv.x + qs[u * 4 + 1] * kv.y
               + qs[u * 4 + 2] * kv.z + qs[u * 4 + 3] * kv.w;
        }
        p *= RSQRT_DK;
        sc[j] = p;
        lmax = fmaxf(lmax, p);
    }
    #pragma unroll
    for (int off = 32; off; off >>= 1) lmax = fmaxf(lmax, __shfl_xor(lmax, off, 64));
    if ((tid & 63) == 0) wred[tid >> 6] = lmax;
    __syncthreads();
    const float m = fmaxf(fmaxf(wred[0], wred[1]), fmaxf(wred[2], wred[3]));

    // phase 2: exp + sum
    float lsum = 0.f;
    for (int j = tid; j < L_; j += 256) {
        float e = __expf(sc[j] - m);
        sc[j] = e;
        lsum += e;
    }
    #pragma unroll
    for (int off = 32; off; off >>= 1) lsum += __shfl_xor(lsum, off, 64);
    if ((tid & 63) == 0) wsum[tid >> 6] = lsum;
    __syncthreads();
    const float Z = wsum[0] + wsum[1] + wsum[2] + wsum[3];

    // phase 3: z[d] = sum_j e_j * v[j][d] / Z
    const int d = tid & 31, g = tid >> 5;
    float acc = 0.f;
    const int j0 = g * (L_ / 8), j1 = j0 + (L_ / 8);
    for (int j = j0; j < j1; ++j)
        acc += sc[j] * vb[(size_t)j * DK_ + d];
    pz[g][d] = acc;
    __syncthreads();
    if (g == 0) {
        float ssum = 0.f;
        #pragma unroll
        for (int gg = 0; gg < 8; ++gg) ssum += pz[gg][d];
        const int b = bh >> 3, h = bh & 7;
        z[((size_t)(b * L_ + r)) * HD_ + h * DK_ + d] = ssum / Z;
    }
}

// ---------------------------------------------------------------------------
// Output GEMM: out = z (4096x256) @ WO (256x256) + bO, flat row-major store.
// ---------------------------------------------------------------------------
__global__ __launch_bounds__(256) void gemm_out_kernel(
    const float* __restrict__ Zm, const float* __restrict__ WO,
    const float* __restrict__ bO, float* __restrict__ out)
{
    const int mt = blockIdx.x;   // 64
    const int nt = blockIdx.y;   // 4

    __shared__ float As[16][64];
    __shared__ float Bs[16][64];

    const int tid = threadIdx.x;
    const int tx = tid & 15, ty = tid >> 4;
    const int m0 = mt * 64, n0 = nt * 64;

    const int arow = tid >> 2, akv = (tid & 3) * 4;
    const int bkk = tid >> 4, bn4 = (tid & 15) * 4;

    float acc[4][4] = {};

    for (int k0 = 0; k0 < HD_; k0 += 16) {
        float4 a4 = *reinterpret_cast<const float4*>(&Zm[(size_t)(m0 + arow) * HD_ + k0 + akv]);
        float4 b4 = *reinterpret_cast<const float4*>(&WO[(size_t)(k0 + bkk) * C_ + n0 + bn4]);
        __syncthreads();
        As[akv + 0][arow] = a4.x;
        As[akv + 1][arow] = a4.y;
        As[akv + 2][arow] = a4.z;
        As[akv + 3][arow] = a4.w;
        *reinterpret_cast<float4*>(&Bs[bkk][bn4]) = b4;
        __syncthreads();
        #pragma unroll
        for (int kk = 0; kk < 16; ++kk) {
            float4 av = *reinterpret_cast<const float4*>(&As[kk][ty * 4]);
            float4 bv = *reinterpret_cast<const float4*>(&Bs[kk][tx * 4]);
            float ar[4] = {av.x, av.y, av.z, av.w};
            float br[4] = {bv.x, bv.y, bv.z, bv.w};
            #pragma unroll
            for (int i = 0; i < 4; ++i)
                #pragma unroll
                for (int j = 0; j < 4; ++j)
                    acc[i][j] += ar[i] * br[j];
        }
    }

    const int col = n0 + tx * 4;
    float4 bb = *reinterpret_cast<const float4*>(&bO[col]);
    #pragma unroll
    for (int i = 0; i < 4; ++i) {
        int mr = m0 + ty * 4 + i;
        float4 o;
        o.x = acc[i][0] + bb.x;
        o.y = acc[i][1] + bb.y;
        o.z = acc[i][2] + bb.z;
        o.w = acc[i][3] + bb.w;
        *reinterpret_cast<float4*>(&out[(size_t)mr * C_ + col]) = o;
    }
}

// ---------------------------------------------------------------------------
extern "C" void kernel_launch(void* const* d_in, const int* in_sizes, int n_in,
                              void* d_out, int out_size, void* d_ws, size_t ws_size,
                              hipStream_t stream)
{
    const float* qx = (const float*)d_in[0];
    const float* kx = (const float*)d_in[1];
    const float* vx = (const float*)d_in[2];
    const float* WQ = (const float*)d_in[3];
    const float* bQ = (const float*)d_in[4];
    const float* WK = (const float*)d_in[5];
    const float* bK = (const float*)d_in[6];
    const float* WV = (const float*)d_in[7];
    const float* bV = (const float*)d_in[8];
    const float* WO = (const float*)d_in[9];
    const float* bO = (const float*)d_in[10];
    float* out = (float*)d_out;

    float* ws = (float*)d_ws;
    const size_t SZ = (size_t)B_ * H_ * L_ * DK_;  // 1,048,576 floats
    float* q    = ws;
    float* k    = ws + SZ;
    float* v    = ws + 2 * SZ;
    float* z    = ws + 3 * SZ;
    float* vsum = ws + 4 * SZ;

    gemm_qkv_kernel<<<dim3(64, 12), 256, 0, stream>>>(qx, kx, vx, WQ, bQ, WK, bK, WV, bV, ws);
    vsum_kernel<<<16, 256, 0, stream>>>(v, vsum);
    attn_interior_kernel<<<4092, 256, 0, stream>>>(q, k, v, vsum, z);
    attn_global_kernel<<<32, 256, 0, stream>>>(q, k, v, z);
    gemm_out_kernel<<<dim3(64, 4), 256, 0, stream>>>(z, WO, bO, out);
}

// Round 2
// 77.489 us; speedup vs baseline: 1.6864x; 1.6864x over previous
//
#include <hip/hip_runtime.h>
#include <hip/hip_bf16.h>

#define B_   2
#define L_   2048
#define C_   256
#define H_   8
#define DK_  32
#define HD_  256
#define RSQRT_DK 0.17677669529663687f  // 1/sqrt(32)

// ---------------------------------------------------------------------------
// Fused QKV projection GEMM, 128x128 tile, 8x8 per-thread micro-tile.
// For proj p in {Q,K,V}: out_p = in_p (4096x256) @ W_p (256x256) + b_p,
// stored into (B,H,L,DK) layout in workspace.
// Grid: (32 m-tiles, 6) where blockIdx.y = proj*2 + n-tile.
// LDS rows padded to 132 floats (528 B) to stagger staging-store banks.
// ---------------------------------------------------------------------------
__global__ __launch_bounds__(256) void gemm_qkv_kernel(
    const float* __restrict__ qx, const float* __restrict__ kx, const float* __restrict__ vx,
    const float* __restrict__ WQ, const float* __restrict__ bQ,
    const float* __restrict__ WK, const float* __restrict__ bK,
    const float* __restrict__ WV, const float* __restrict__ bV,
    float* __restrict__ ws)
{
    const int mt = blockIdx.x;          // 0..31
    const int yy = blockIdx.y;          // 0..5
    const int proj = yy >> 1;
    const int nt = yy & 1;
    const float* A    = proj == 0 ? qx : (proj == 1 ? kx : vx);
    const float* W    = proj == 0 ? WQ : (proj == 1 ? WK : WV);
    const float* bias = proj == 0 ? bQ : (proj == 1 ? bK : bV);
    float* out = ws + (size_t)proj * (B_ * H_ * L_ * DK_);

    __shared__ float As[16][132];       // [k][m], padded
    __shared__ float Bs[16][132];       // [k][n], padded

    const int tid = threadIdx.x;
    const int tx = tid & 15, ty = tid >> 4;
    const int m0 = mt * 128, n0 = nt * 128;

    // staging thread mapping
    const int ar = tid >> 2;            // 0..63 (rows; +64 for second half)
    const int ak = (tid & 3) * 4;       // k within step
    const int bk = tid >> 4;            // 0..15 (k row)
    const int bn = (tid & 15) * 4;      // 0..60 (cols; +64 for second half)

    // prefetch K-step 0 into registers
    float4 a0 = *reinterpret_cast<const float4*>(&A[(size_t)(m0 + ar) * C_ + ak]);
    float4 a1 = *reinterpret_cast<const float4*>(&A[(size_t)(m0 + ar + 64) * C_ + ak]);
    float4 b0 = *reinterpret_cast<const float4*>(&W[(size_t)bk * HD_ + n0 + bn]);
    float4 b1 = *reinterpret_cast<const float4*>(&W[(size_t)bk * HD_ + n0 + bn + 64]);

    float acc[8][8] = {};

    for (int k0 = 0; k0 < C_; k0 += 16) {
        __syncthreads();
        As[ak + 0][ar] = a0.x;  As[ak + 1][ar] = a0.y;
        As[ak + 2][ar] = a0.z;  As[ak + 3][ar] = a0.w;
        As[ak + 0][ar + 64] = a1.x;  As[ak + 1][ar + 64] = a1.y;
        As[ak + 2][ar + 64] = a1.z;  As[ak + 3][ar + 64] = a1.w;
        *reinterpret_cast<float4*>(&Bs[bk][bn])      = b0;
        *reinterpret_cast<float4*>(&Bs[bk][bn + 64]) = b1;
        __syncthreads();
        if (k0 + 16 < C_) {
            const int kn = k0 + 16;
            a0 = *reinterpret_cast<const float4*>(&A[(size_t)(m0 + ar) * C_ + kn + ak]);
            a1 = *reinterpret_cast<const float4*>(&A[(size_t)(m0 + ar + 64) * C_ + kn + ak]);
            b0 = *reinterpret_cast<const float4*>(&W[(size_t)(kn + bk) * HD_ + n0 + bn]);
            b1 = *reinterpret_cast<const float4*>(&W[(size_t)(kn + bk) * HD_ + n0 + bn + 64]);
        }
        #pragma unroll
        for (int kk = 0; kk < 16; ++kk) {
            float4 x0 = *reinterpret_cast<const float4*>(&As[kk][ty * 8]);
            float4 x1 = *reinterpret_cast<const float4*>(&As[kk][ty * 8 + 4]);
            float4 y0 = *reinterpret_cast<const float4*>(&Bs[kk][tx * 8]);
            float4 y1 = *reinterpret_cast<const float4*>(&Bs[kk][tx * 8 + 4]);
            float av[8] = {x0.x, x0.y, x0.z, x0.w, x1.x, x1.y, x1.z, x1.w};
            float bv[8] = {y0.x, y0.y, y0.z, y0.w, y1.x, y1.y, y1.z, y1.w};
            #pragma unroll
            for (int i = 0; i < 8; ++i)
                #pragma unroll
                for (int j = 0; j < 8; ++j)
                    acc[i][j] += av[i] * bv[j];
        }
    }

    // epilogue: bias + scatter to (B,H,L,DK)
    const int col = n0 + tx * 8;            // multiple of 8 -> never crosses head
    const int h = col >> 5, d = col & 31;
    float4 bb0 = *reinterpret_cast<const float4*>(&bias[col]);
    float4 bb1 = *reinterpret_cast<const float4*>(&bias[col + 4]);
    #pragma unroll
    for (int i = 0; i < 8; ++i) {
        int mr = m0 + ty * 8 + i;
        int b = mr >> 11, l = mr & (L_ - 1);
        float* o = &out[((size_t)(b * H_ + h) * L_ + l) * DK_ + d];
        float4 o0, o1;
        o0.x = acc[i][0] + bb0.x;  o0.y = acc[i][1] + bb0.y;
        o0.z = acc[i][2] + bb0.z;  o0.w = acc[i][3] + bb0.w;
        o1.x = acc[i][4] + bb1.x;  o1.y = acc[i][5] + bb1.y;
        o1.z = acc[i][6] + bb1.z;  o1.w = acc[i][7] + bb1.w;
        *reinterpret_cast<float4*>(o)     = o0;
        *reinterpret_cast<float4*>(o + 4) = o1;
    }
}

// ---------------------------------------------------------------------------
// vsum stage A: 256 blocks = (bh, 128-row chunk); partial col-sums of V.
// ---------------------------------------------------------------------------
__global__ __launch_bounds__(256) void vsum_part_kernel(
    const float* __restrict__ v, float* __restrict__ part)
{
    const int blk = blockIdx.x;          // bh*16 + chunk
    const int bh = blk >> 4, chunk = blk & 15;
    const int tid = threadIdx.x;
    const int d = tid & 31, g = tid >> 5;
    const float* vb = v + ((size_t)bh * L_ + chunk * 128) * DK_;
    float acc = 0.f;
    #pragma unroll 4
    for (int r = 0; r < 16; ++r) acc += vb[(g * 16 + r) * DK_ + d];
    __shared__ float red[8][32];
    red[g][d] = acc;
    __syncthreads();
    if (g == 0) {
        float s = 0.f;
        #pragma unroll
        for (int gg = 0; gg < 8; ++gg) s += red[gg][d];
        part[(size_t)blk * 32 + d] = s;
    }
}

// vsum stage B: one block, 512 threads: vsum[bh][d] = sum over 16 chunks.
__global__ __launch_bounds__(512) void vsum_final_kernel(
    const float* __restrict__ part, float* __restrict__ vsum)
{
    const int t = threadIdx.x;           // 0..511
    const int bh = t >> 5, d = t & 31;
    float s = 0.f;
    #pragma unroll
    for (int c = 0; c < 16; ++c) s += part[((size_t)bh * 16 + c) * 32 + d];
    vsum[bh * DK_ + d] = s;
}

// ---------------------------------------------------------------------------
// Interior rows i in [1, L-2]: sparse softmax over S_i = {0, i-1, i, i+1, L-1}
// plus (L - |S_i|) zero-score entries. One 32-lane group per row, lane = dim d.
// ---------------------------------------------------------------------------
__global__ __launch_bounds__(256) void attn_interior_kernel(
    const float* __restrict__ q, const float* __restrict__ k,
    const float* __restrict__ v, const float* __restrict__ vsum,
    float* __restrict__ z)
{
    const int tid = threadIdx.x;
    const int d = tid & 31, rg = tid >> 5;
    const long gidx = (long)blockIdx.x * 8 + rg;       // global row-group index
    const int rowsPerBH = L_ - 2;                      // 2046
    const int bh = (int)(gidx / rowsPerBH);
    if (bh >= B_ * H_) return;
    const int i = 1 + (int)(gidx % rowsPerBH);

    const float* qb = q + (size_t)bh * L_ * DK_;
    const float* kb = k + (size_t)bh * L_ * DK_;
    const float* vb = v + (size_t)bh * L_ * DK_;

    const float qd = qb[i * DK_ + d];

    int cols[5] = {0, i - 1, i, i + 1, L_ - 1};
    bool valid[5] = {true, i != 1, true, i != L_ - 2, true};

    float s[5];
    #pragma unroll
    for (int jj = 0; jj < 5; ++jj) {
        float p = qd * kb[cols[jj] * DK_ + d];
        #pragma unroll
        for (int off = 16; off; off >>= 1) p += __shfl_xor(p, off, 32);
        s[jj] = p * RSQRT_DK;
    }

    float m = 0.f;  // zero-score filler entries participate in the row max
    int ns = 0;
    #pragma unroll
    for (int jj = 0; jj < 5; ++jj) {
        if (valid[jj]) { m = fmaxf(m, s[jj]); ns++; }
    }

    float e[5], sume = 0.f;
    #pragma unroll
    for (int jj = 0; jj < 5; ++jj) {
        e[jj] = valid[jj] ? __expf(s[jj] - m) : 0.f;
        sume += e[jj];
    }
    const float e0 = __expf(-m);
    const float Z = sume + (float)(L_ - ns) * e0;

    float zd = 0.f, vp = 0.f;
    #pragma unroll
    for (int jj = 0; jj < 5; ++jj) {
        float vd = vb[cols[jj] * DK_ + d];
        zd += e[jj] * vd;
        vp += valid[jj] ? vd : 0.f;
    }
    zd += e0 * (vsum[bh * DK_ + d] - vp);
    zd /= Z;

    const int b = bh >> 3, h = bh & 7;
    z[((size_t)(b * L_ + i)) * HD_ + h * DK_ + d] = zd;
}

// ---------------------------------------------------------------------------
// Global rows (i = 0 and i = L-1): fully dense row of real scores.
// One block per (b,h,row). 32 blocks total.
// ---------------------------------------------------------------------------
__global__ __launch_bounds__(256) void attn_global_kernel(
    const float* __restrict__ q, const float* __restrict__ k,
    const float* __restrict__ v, float* __restrict__ z)
{
    const int blk = blockIdx.x;          // 0..31
    const int bh = blk >> 1;
    const int r = (blk & 1) ? (L_ - 1) : 0;
    const float* qb = q + (size_t)bh * L_ * DK_;
    const float* kb = k + (size_t)bh * L_ * DK_;
    const float* vb = v + (size_t)bh * L_ * DK_;

    __shared__ float sc[L_];             // 8 KB scores/weights
    __shared__ float qs[DK_];
    __shared__ float wred[4], wsum[4];
    __shared__ float pz[8][32];

    const int tid = threadIdx.x;
    if (tid < DK_) qs[tid] = qb[r * DK_ + tid];
    __syncthreads();

    // phase 1: scores + local max
    float lmax = -1e30f;
    for (int j = tid; j < L_; j += 256) {
        const float4* kr = reinterpret_cast<const float4*>(&kb[(size_t)j * DK_]);
        float p = 0.f;
        #pragma unroll
        for (int u = 0; u < 8; ++u) {
            float4 kv = kr[u];
            p += qs[u * 4 + 0] * kv.x + qs[u * 4 + 1] * kv.y
               + qs[u * 4 + 2] * kv.z + qs[u * 4 + 3] * kv.w;
        }
        p *= RSQRT_DK;
        sc[j] = p;
        lmax = fmaxf(lmax, p);
    }
    #pragma unroll
    for (int off = 32; off; off >>= 1) lmax = fmaxf(lmax, __shfl_xor(lmax, off, 64));
    if ((tid & 63) == 0) wred[tid >> 6] = lmax;
    __syncthreads();
    const float m = fmaxf(fmaxf(wred[0], wred[1]), fmaxf(wred[2], wred[3]));

    // phase 2: exp + sum
    float lsum = 0.f;
    for (int j = tid; j < L_; j += 256) {
        float e = __expf(sc[j] - m);
        sc[j] = e;
        lsum += e;
    }
    #pragma unroll
    for (int off = 32; off; off >>= 1) lsum += __shfl_xor(lsum, off, 64);
    if ((tid & 63) == 0) wsum[tid >> 6] = lsum;
    __syncthreads();
    const float Z = wsum[0] + wsum[1] + wsum[2] + wsum[3];

    // phase 3: z[d] = sum_j e_j * v[j][d] / Z
    const int d = tid & 31, g = tid >> 5;
    float acc = 0.f;
    const int j0 = g * (L_ / 8), j1 = j0 + (L_ / 8);
    for (int j = j0; j < j1; ++j)
        acc += sc[j] * vb[(size_t)j * DK_ + d];
    pz[g][d] = acc;
    __syncthreads();
    if (g == 0) {
        float ssum = 0.f;
        #pragma unroll
        for (int gg = 0; gg < 8; ++gg) ssum += pz[gg][d];
        const int b = bh >> 3, h = bh & 7;
        z[((size_t)(b * L_ + r)) * HD_ + h * DK_ + d] = ssum / Z;
    }
}

// ---------------------------------------------------------------------------
// Output GEMM: out = z (4096x256) @ WO (256x256) + bO, flat row-major store.
// 64x64 tile, 4x4 micro-tile, register prefetch. Padded LDS (68).
// ---------------------------------------------------------------------------
__global__ __launch_bounds__(256) void gemm_out_kernel(
    const float* __restrict__ Zm, const float* __restrict__ WO,
    const float* __restrict__ bO, float* __restrict__ out)
{
    const int mt = blockIdx.x;   // 64
    const int nt = blockIdx.y;   // 4

    __shared__ float As[16][68];
    __shared__ float Bs[16][68];

    const int tid = threadIdx.x;
    const int tx = tid & 15, ty = tid >> 4;
    const int m0 = mt * 64, n0 = nt * 64;

    const int arow = tid >> 2, akv = (tid & 3) * 4;
    const int bkk = tid >> 4, bn4 = (tid & 15) * 4;

    float4 a4 = *reinterpret_cast<const float4*>(&Zm[(size_t)(m0 + arow) * HD_ + akv]);
    float4 b4 = *reinterpret_cast<const float4*>(&WO[(size_t)bkk * C_ + n0 + bn4]);

    float acc[4][4] = {};

    for (int k0 = 0; k0 < HD_; k0 += 16) {
        __syncthreads();
        As[akv + 0][arow] = a4.x;
        As[akv + 1][arow] = a4.y;
        As[akv + 2][arow] = a4.z;
        As[akv + 3][arow] = a4.w;
        *reinterpret_cast<float4*>(&Bs[bkk][bn4]) = b4;
        __syncthreads();
        if (k0 + 16 < HD_) {
            const int kn = k0 + 16;
            a4 = *reinterpret_cast<const float4*>(&Zm[(size_t)(m0 + arow) * HD_ + kn + akv]);
            b4 = *reinterpret_cast<const float4*>(&WO[(size_t)(kn + bkk) * C_ + n0 + bn4]);
        }
        #pragma unroll
        for (int kk = 0; kk < 16; ++kk) {
            float4 av = *reinterpret_cast<const float4*>(&As[kk][ty * 4]);
            float4 bv = *reinterpret_cast<const float4*>(&Bs[kk][tx * 4]);
            float ar[4] = {av.x, av.y, av.z, av.w};
            float br[4] = {bv.x, bv.y, bv.z, bv.w};
            #pragma unroll
            for (int i = 0; i < 4; ++i)
                #pragma unroll
                for (int j = 0; j < 4; ++j)
                    acc[i][j] += ar[i] * br[j];
        }
    }

    const int col = n0 + tx * 4;
    float4 bb = *reinterpret_cast<const float4*>(&bO[col]);
    #pragma unroll
    for (int i = 0; i < 4; ++i) {
        int mr = m0 + ty * 4 + i;
        float4 o;
        o.x = acc[i][0] + bb.x;
        o.y = acc[i][1] + bb.y;
        o.z = acc[i][2] + bb.z;
        o.w = acc[i][3] + bb.w;
        *reinterpret_cast<float4*>(&out[(size_t)mr * C_ + col]) = o;
    }
}

// ---------------------------------------------------------------------------
extern "C" void kernel_launch(void* const* d_in, const int* in_sizes, int n_in,
                              void* d_out, int out_size, void* d_ws, size_t ws_size,
                              hipStream_t stream)
{
    const float* qx = (const float*)d_in[0];
    const float* kx = (const float*)d_in[1];
    const float* vx = (const float*)d_in[2];
    const float* WQ = (const float*)d_in[3];
    const float* bQ = (const float*)d_in[4];
    const float* WK = (const float*)d_in[5];
    const float* bK = (const float*)d_in[6];
    const float* WV = (const float*)d_in[7];
    const float* bV = (const float*)d_in[8];
    const float* WO = (const float*)d_in[9];
    const float* bO = (const float*)d_in[10];
    float* out = (float*)d_out;

    float* ws = (float*)d_ws;
    const size_t SZ = (size_t)B_ * H_ * L_ * DK_;  // 1,048,576 floats
    float* q    = ws;
    float* k    = ws + SZ;
    float* v    = ws + 2 * SZ;
    float* z    = ws + 3 * SZ;
    float* vsum = ws + 4 * SZ;
    // vsum partials alias the z region: produced+consumed before z is written.
    float* part = z;

    gemm_qkv_kernel<<<dim3(32, 6), 256, 0, stream>>>(qx, kx, vx, WQ, bQ, WK, bK, WV, bV, ws);
    vsum_part_kernel<<<256, 256, 0, stream>>>(v, part);
    vsum_final_kernel<<<1, 512, 0, stream>>>(part, vsum);
    attn_interior_kernel<<<4092, 256, 0, stream>>>(q, k, v, vsum, z);
    attn_global_kernel<<<32, 256, 0, stream>>>(q, k, v, z);
    gemm_out_kernel<<<dim3(64, 4), 256, 0, stream>>>(z, WO, bO, out);
}

// Round 3
// 62.667 us; speedup vs baseline: 2.0852x; 1.2365x over previous
//
#include <hip/hip_runtime.h>
#include <hip/hip_bf16.h>

#define B_   2
#define L_   2048
#define C_   256
#define H_   8
#define DK_  32
#define HD_  256
#define RSQRT_DK 0.17677669529663687f  // 1/sqrt(32)

typedef __attribute__((ext_vector_type(8))) short bf16x8;
typedef __attribute__((ext_vector_type(4))) float f32x4;

__device__ __forceinline__ unsigned short f2bf(float x) {
    unsigned int u = __float_as_uint(x);
    u += 0x7fffu + ((u >> 16) & 1u);
    return (unsigned short)(u >> 16);
}
__device__ __forceinline__ float bf2f(unsigned short h) {
    return __uint_as_float((unsigned int)h << 16);
}

// ---------------------------------------------------------------------------
// Transpose + split-bf16 convert all four weight matrices (256x256 fp32,
// [k][n]) into WT[p] = hi/lo bf16 [n][k].  p = 0..3 : WQ, WK, WV, WO.
// Grid 64 blocks x 256 thr: block = (p, 64x64 tile).
// ---------------------------------------------------------------------------
__global__ __launch_bounds__(256) void transpose_w_kernel(
    const float* __restrict__ WQ, const float* __restrict__ WK,
    const float* __restrict__ WV, const float* __restrict__ WO,
    unsigned short* __restrict__ wT)
{
    const int blk = blockIdx.x;
    const int p = blk >> 4, tile = blk & 15;
    const int k0 = (tile >> 2) * 64, n0 = (tile & 3) * 64;
    const float* W = p == 0 ? WQ : (p == 1 ? WK : (p == 2 ? WV : WO));
    unsigned short* Th = wT + (size_t)p * 131072;
    unsigned short* Tl = Th + 65536;

    __shared__ float ts[64][65];
    const int t = threadIdx.x;
    const int r = t >> 2, cq = (t & 3) * 16;
    #pragma unroll
    for (int u = 0; u < 4; ++u) {
        float4 w4 = *reinterpret_cast<const float4*>(&W[(size_t)(k0 + r) * 256 + n0 + cq + u * 4]);
        ts[r][cq + u * 4 + 0] = w4.x;
        ts[r][cq + u * 4 + 1] = w4.y;
        ts[r][cq + u * 4 + 2] = w4.z;
        ts[r][cq + u * 4 + 3] = w4.w;
    }
    __syncthreads();
    bf16x8 hv0, hv1, lv0, lv1;
    #pragma unroll
    for (int e = 0; e < 8; ++e) {
        float x0 = ts[cq + e][r];
        float x1 = ts[cq + 8 + e][r];
        unsigned short h0 = f2bf(x0), h1 = f2bf(x1);
        hv0[e] = (short)h0;  lv0[e] = (short)f2bf(x0 - bf2f(h0));
        hv1[e] = (short)h1;  lv1[e] = (short)f2bf(x1 - bf2f(h1));
    }
    const size_t o = (size_t)(n0 + r) * 256 + k0 + cq;
    *reinterpret_cast<bf16x8*>(&Th[o])     = hv0;
    *reinterpret_cast<bf16x8*>(&Th[o + 8]) = hv1;
    *reinterpret_cast<bf16x8*>(&Tl[o])     = lv0;
    *reinterpret_cast<bf16x8*>(&Tl[o + 8]) = lv1;
}

// ---------------------------------------------------------------------------
// QKV projection via split-bf16 MFMA.  One wave per block; wave tile 32x64.
// Grid (128 m-tiles, 12 = proj*4 + nt).  A read fp32 + converted on the fly;
// B frags read directly from pre-transposed WT (bf16 [n][k]).  No LDS.
// out stored to (B,H,L,DK) fp32.
// ---------------------------------------------------------------------------
__global__ __launch_bounds__(64) void gemm_qkv_mfma(
    const float* __restrict__ qx, const float* __restrict__ kx, const float* __restrict__ vx,
    const float* __restrict__ bQ, const float* __restrict__ bK, const float* __restrict__ bV,
    const unsigned short* __restrict__ wT,
    float* __restrict__ q, float* __restrict__ k, float* __restrict__ v)
{
    const int bx = blockIdx.x;          // 0..127
    const int yy = blockIdx.y;          // 0..11
    const int proj = yy >> 2, nt = yy & 3;
    const float* A    = proj == 0 ? qx : (proj == 1 ? kx : vx);
    const float* bias = proj == 0 ? bQ : (proj == 1 ? bK : bV);
    float* out        = proj == 0 ? q  : (proj == 1 ? k  : v);
    const unsigned short* WTh = wT + (size_t)proj * 131072;
    const unsigned short* WTl = WTh + 65536;

    const int l  = threadIdx.x;
    const int lm = l & 15, lk = (l >> 4) * 8;
    const int R = bx * 32, n0 = nt * 64;

    f32x4 acc[2][4];
    #pragma unroll
    for (int mf = 0; mf < 2; ++mf)
        #pragma unroll
        for (int nf = 0; nf < 4; ++nf)
            acc[mf][nf] = (f32x4){0.f, 0.f, 0.f, 0.f};

    float4 Ab[3][4];
    bf16x8 Bh[3][4], Bl[3][4];

    #define QKV_LOAD(s, ks)                                                              \
    {                                                                                    \
        const float* pa0 = &A[(size_t)(R + lm) * 256 + (ks) * 32 + lk];                  \
        const float* pa1 = &A[(size_t)(R + 16 + lm) * 256 + (ks) * 32 + lk];             \
        Ab[s][0] = *reinterpret_cast<const float4*>(pa0);                                \
        Ab[s][1] = *reinterpret_cast<const float4*>(pa0 + 4);                            \
        Ab[s][2] = *reinterpret_cast<const float4*>(pa1);                                \
        Ab[s][3] = *reinterpret_cast<const float4*>(pa1 + 4);                            \
        _Pragma("unroll")                                                                \
        for (int nf = 0; nf < 4; ++nf) {                                                 \
            size_t o = (size_t)(n0 + nf * 16 + lm) * 256 + (ks) * 32 + lk;               \
            Bh[s][nf] = *reinterpret_cast<const bf16x8*>(&WTh[o]);                       \
            Bl[s][nf] = *reinterpret_cast<const bf16x8*>(&WTl[o]);                       \
        }                                                                                \
    }

    QKV_LOAD(0, 0)
    QKV_LOAD(1, 1)

    #pragma unroll
    for (int ks = 0; ks < 8; ++ks) {
        const int cur = ks % 3, nxt = (ks + 2) % 3;
        if (ks < 6) QKV_LOAD(nxt, ks + 2)
        bf16x8 ah[2], al[2];
        #pragma unroll
        for (int mf = 0; mf < 2; ++mf) {
            float4 v0 = Ab[cur][mf * 2], v1 = Ab[cur][mf * 2 + 1];
            float xs[8] = {v0.x, v0.y, v0.z, v0.w, v1.x, v1.y, v1.z, v1.w};
            #pragma unroll
            for (int e = 0; e < 8; ++e) {
                unsigned short h = f2bf(xs[e]);
                ah[mf][e] = (short)h;
                al[mf][e] = (short)f2bf(xs[e] - bf2f(h));
            }
        }
        #pragma unroll
        for (int mf = 0; mf < 2; ++mf)
            #pragma unroll
            for (int nf = 0; nf < 4; ++nf) {
                acc[mf][nf] = __builtin_amdgcn_mfma_f32_16x16x32_bf16(ah[mf], Bh[cur][nf], acc[mf][nf], 0, 0, 0);
                acc[mf][nf] = __builtin_amdgcn_mfma_f32_16x16x32_bf16(ah[mf], Bl[cur][nf], acc[mf][nf], 0, 0, 0);
                acc[mf][nf] = __builtin_amdgcn_mfma_f32_16x16x32_bf16(al[mf], Bh[cur][nf], acc[mf][nf], 0, 0, 0);
            }
    }
    #undef QKV_LOAD

    const int cr = (l >> 4) * 4;
    #pragma unroll
    for (int mf = 0; mf < 2; ++mf)
        #pragma unroll
        for (int nf = 0; nf < 4; ++nf) {
            const int col = n0 + nf * 16 + lm;
            const int h = col >> 5, d = col & 31;
            const float bb = bias[col];
            #pragma unroll
            for (int r = 0; r < 4; ++r) {
                const int m = R + mf * 16 + cr + r;
                const int b = m >> 11, lrow = m & (L_ - 1);
                out[((size_t)(b * H_ + h) * L_ + lrow) * DK_ + d] = acc[mf][nf][r] + bb;
            }
        }
}

// ---------------------------------------------------------------------------
// vsum stage A: 256 blocks = (bh, 128-row chunk); partial col-sums of V.
// ---------------------------------------------------------------------------
__global__ __launch_bounds__(256) void vsum_part_kernel(
    const float* __restrict__ v, float* __restrict__ part)
{
    const int blk = blockIdx.x;
    const int bh = blk >> 4, chunk = blk & 15;
    const int tid = threadIdx.x;
    const int d = tid & 31, g = tid >> 5;
    const float* vb = v + ((size_t)bh * L_ + chunk * 128) * DK_;
    float acc = 0.f;
    #pragma unroll 4
    for (int r = 0; r < 16; ++r) acc += vb[(g * 16 + r) * DK_ + d];
    __shared__ float red[8][32];
    red[g][d] = acc;
    __syncthreads();
    if (g == 0) {
        float s = 0.f;
        #pragma unroll
        for (int gg = 0; gg < 8; ++gg) s += red[gg][d];
        part[(size_t)blk * 32 + d] = s;
    }
}

__global__ __launch_bounds__(512) void vsum_final_kernel(
    const float* __restrict__ part, float* __restrict__ vsum)
{
    const int t = threadIdx.x;
    const int bh = t >> 5, d = t & 31;
    float s = 0.f;
    #pragma unroll
    for (int c = 0; c < 16; ++c) s += part[((size_t)bh * 16 + c) * 32 + d];
    vsum[bh * DK_ + d] = s;
}

// ---------------------------------------------------------------------------
// Interior rows i in [1, L-2]: sparse softmax over S_i = {0, i-1, i, i+1, L-1}
// plus (L-|S_i|) zero-score entries.  Writes z as split-bf16 hi/lo.
// ---------------------------------------------------------------------------
__global__ __launch_bounds__(256) void attn_interior_kernel(
    const float* __restrict__ q, const float* __restrict__ k,
    const float* __restrict__ v, const float* __restrict__ vsum,
    unsigned short* __restrict__ zh, unsigned short* __restrict__ zl)
{
    const int tid = threadIdx.x;
    const int d = tid & 31, rg = tid >> 5;
    const long gidx = (long)blockIdx.x * 8 + rg;
    const int rowsPerBH = L_ - 2;
    const int bh = (int)(gidx / rowsPerBH);
    if (bh >= B_ * H_) return;
    const int i = 1 + (int)(gidx % rowsPerBH);

    const float* qb = q + (size_t)bh * L_ * DK_;
    const float* kb = k + (size_t)bh * L_ * DK_;
    const float* vb = v + (size_t)bh * L_ * DK_;

    const float qd = qb[i * DK_ + d];

    int cols[5] = {0, i - 1, i, i + 1, L_ - 1};
    bool valid[5] = {true, i != 1, true, i != L_ - 2, true};

    float s[5];
    #pragma unroll
    for (int jj = 0; jj < 5; ++jj) {
        float p = qd * kb[cols[jj] * DK_ + d];
        #pragma unroll
        for (int off = 16; off; off >>= 1) p += __shfl_xor(p, off, 32);
        s[jj] = p * RSQRT_DK;
    }

    float m = 0.f;
    int ns = 0;
    #pragma unroll
    for (int jj = 0; jj < 5; ++jj) {
        if (valid[jj]) { m = fmaxf(m, s[jj]); ns++; }
    }

    float e[5], sume = 0.f;
    #pragma unroll
    for (int jj = 0; jj < 5; ++jj) {
        e[jj] = valid[jj] ? __expf(s[jj] - m) : 0.f;
        sume += e[jj];
    }
    const float e0 = __expf(-m);
    const float Z = sume + (float)(L_ - ns) * e0;

    float zd = 0.f, vp = 0.f;
    #pragma unroll
    for (int jj = 0; jj < 5; ++jj) {
        float vd = vb[cols[jj] * DK_ + d];
        zd += e[jj] * vd;
        vp += valid[jj] ? vd : 0.f;
    }
    zd += e0 * (vsum[bh * DK_ + d] - vp);
    zd /= Z;

    const int b = bh >> 3, h = bh & 7;
    const size_t o = (size_t)(b * L_ + i) * HD_ + h * DK_ + d;
    const unsigned short hb = f2bf(zd);
    zh[o] = hb;
    zl[o] = f2bf(zd - bf2f(hb));
}

// ---------------------------------------------------------------------------
// Global rows, stage 1: 256 blocks = (bh, row-pair, 256-col chunk).
// Per-chunk partial softmax: local max, exp-sum, partial weighted V.
// ---------------------------------------------------------------------------
__global__ __launch_bounds__(256) void attn_g1_kernel(
    const float* __restrict__ q, const float* __restrict__ k,
    const float* __restrict__ v,
    float* __restrict__ pm, float* __restrict__ pZ, float* __restrict__ pzv)
{
    const int blk = blockIdx.x;          // 0..255
    const int bh = blk >> 4;
    const int pair = (blk >> 3) & 1;
    const int chunk = blk & 7;
    const int r = pair ? (L_ - 1) : 0;
    const int j0 = chunk * 256;

    const float* qb = q + (size_t)bh * L_ * DK_;
    const float* kb = k + (size_t)bh * L_ * DK_;
    const float* vb = v + (size_t)bh * L_ * DK_;

    __shared__ float qs[DK_];
    __shared__ float sc[256];
    __shared__ float redm[4], reds[4];
    __shared__ float pz[8][32];

    const int t = threadIdx.x;
    if (t < DK_) qs[t] = qb[r * DK_ + t];
    __syncthreads();

    const float4* kr = reinterpret_cast<const float4*>(&kb[(size_t)(j0 + t) * DK_]);
    float p = 0.f;
    #pragma unroll
    for (int u = 0; u < 8; ++u) {
        float4 kv = kr[u];
        p += qs[u * 4 + 0] * kv.x + qs[u * 4 + 1] * kv.y
           + qs[u * 4 + 2] * kv.z + qs[u * 4 + 3] * kv.w;
    }
    p *= RSQRT_DK;

    float lm = p;
    #pragma unroll
    for (int off = 32; off; off >>= 1) lm = fmaxf(lm, __shfl_xor(lm, off, 64));
    if ((t & 63) == 0) redm[t >> 6] = lm;
    __syncthreads();
    const float m = fmaxf(fmaxf(redm[0], redm[1]), fmaxf(redm[2], redm[3]));

    const float e = __expf(p - m);
    sc[t] = e;
    float ls = e;
    #pragma unroll
    for (int off = 32; off; off >>= 1) ls += __shfl_xor(ls, off, 64);
    if ((t & 63) == 0) reds[t >> 6] = ls;
    __syncthreads();
    const float Zc = reds[0] + reds[1] + reds[2] + reds[3];

    const int d = t & 31, g = t >> 5;
    float acc = 0.f;
    #pragma unroll 4
    for (int jj = 0; jj < 32; ++jj)
        acc += sc[g * 32 + jj] * vb[(size_t)(j0 + g * 32 + jj) * DK_ + d];
    pz[g][d] = acc;
    __syncthreads();
    if (g == 0) {
        float s = 0.f;
        #pragma unroll
        for (int gg = 0; gg < 8; ++gg) s += pz[gg][d];
        pzv[(size_t)blk * 32 + d] = s;
    }
    if (t == 0) { pm[blk] = m; pZ[blk] = Zc; }
}

// Global rows, stage 2: combine 8 chunks per (bh, pair); write z hi/lo.
__global__ __launch_bounds__(1024) void attn_g2_kernel(
    const float* __restrict__ pm, const float* __restrict__ pZ,
    const float* __restrict__ pzv,
    unsigned short* __restrict__ zh, unsigned short* __restrict__ zl)
{
    const int t = threadIdx.x;           // 0..1023
    const int rowIdx = t >> 5;           // 0..31  (= bh*2 + pair)
    const int d = t & 31;
    const int bh = rowIdx >> 1, pair = rowIdx & 1;
    const int base = rowIdx * 8;

    float m = -1e30f;
    #pragma unroll
    for (int c = 0; c < 8; ++c) m = fmaxf(m, pm[base + c]);
    float Z = 0.f, zd = 0.f;
    #pragma unroll
    for (int c = 0; c < 8; ++c) {
        const float w = __expf(pm[base + c] - m);
        Z  += pZ[base + c] * w;
        zd += pzv[(size_t)(base + c) * 32 + d] * w;
    }
    zd /= Z;

    const int r = pair ? (L_ - 1) : 0;
    const int b = bh >> 3, h = bh & 7;
    const size_t o = (size_t)(b * L_ + r) * HD_ + h * DK_ + d;
    const unsigned short hb = f2bf(zd);
    zh[o] = hb;
    zl[o] = f2bf(zd - bf2f(hb));
}

// ---------------------------------------------------------------------------
// Output GEMM via split-bf16 MFMA: out = z @ WO + bO.  A = zh/zl bf16 [m][k],
// B = WT[3] bf16 [n][k].  One wave/block, tile 32x64, grid (128, 4). No LDS.
// ---------------------------------------------------------------------------
__global__ __launch_bounds__(64) void gemm_out_mfma(
    const unsigned short* __restrict__ zh, const unsigned short* __restrict__ zl,
    const unsigned short* __restrict__ wT, const float* __restrict__ bO,
    float* __restrict__ out)
{
    const int bx = blockIdx.x;          // 0..127
    const int nt = blockIdx.y;          // 0..3
    const unsigned short* WTh = wT + (size_t)3 * 131072;
    const unsigned short* WTl = WTh + 65536;

    const int l  = threadIdx.x;
    const int lm = l & 15, lk = (l >> 4) * 8;
    const int R = bx * 32, n0 = nt * 64;

    f32x4 acc[2][4];
    #pragma unroll
    for (int mf = 0; mf < 2; ++mf)
        #pragma unroll
        for (int nf = 0; nf < 4; ++nf)
            acc[mf][nf] = (f32x4){0.f, 0.f, 0.f, 0.f};

    bf16x8 Ah[3][2], Al[3][2], Bh[3][4], Bl[3][4];

    #define OUT_LOAD(s, ks)                                                              \
    {                                                                                    \
        const size_t o0 = (size_t)(R + lm) * 256 + (ks) * 32 + lk;                       \
        const size_t o1 = (size_t)(R + 16 + lm) * 256 + (ks) * 32 + lk;                  \
        Ah[s][0] = *reinterpret_cast<const bf16x8*>(&zh[o0]);                            \
        Al[s][0] = *reinterpret_cast<const bf16x8*>(&zl[o0]);                            \
        Ah[s][1] = *reinterpret_cast<const bf16x8*>(&zh[o1]);                            \
        Al[s][1] = *reinterpret_cast<const bf16x8*>(&zl[o1]);                            \
        _Pragma("unroll")                                                                \
        for (int nf = 0; nf < 4; ++nf) {                                                 \
            size_t o = (size_t)(n0 + nf * 16 + lm) * 256 + (ks) * 32 + lk;               \
            Bh[s][nf] = *reinterpret_cast<const bf16x8*>(&WTh[o]);                       \
            Bl[s][nf] = *reinterpret_cast<const bf16x8*>(&WTl[o]);                       \
        }                                                                                \
    }

    OUT_LOAD(0, 0)
    OUT_LOAD(1, 1)

    #pragma unroll
    for (int ks = 0; ks < 8; ++ks) {
        const int cur = ks % 3, nxt = (ks + 2) % 3;
        if (ks < 6) OUT_LOAD(nxt, ks + 2)
        #pragma unroll
        for (int mf = 0; mf < 2; ++mf)
            #pragma unroll
            for (int nf = 0; nf < 4; ++nf) {
                acc[mf][nf] = __builtin_amdgcn_mfma_f32_16x16x32_bf16(Ah[cur][mf], Bh[cur][nf], acc[mf][nf], 0, 0, 0);
                acc[mf][nf] = __builtin_amdgcn_mfma_f32_16x16x32_bf16(Ah[cur][mf], Bl[cur][nf], acc[mf][nf], 0, 0, 0);
                acc[mf][nf] = __builtin_amdgcn_mfma_f32_16x16x32_bf16(Al[cur][mf], Bh[cur][nf], acc[mf][nf], 0, 0, 0);
            }
    }
    #undef OUT_LOAD

    const int cr = (l >> 4) * 4;
    #pragma unroll
    for (int mf = 0; mf < 2; ++mf)
        #pragma unroll
        for (int nf = 0; nf < 4; ++nf) {
            const int col = n0 + nf * 16 + lm;
            const float bb = bO[col];
            #pragma unroll
            for (int r = 0; r < 4; ++r) {
                const int m = R + mf * 16 + cr + r;
                out[(size_t)m * 256 + col] = acc[mf][nf][r] + bb;
            }
        }
}

// ---------------------------------------------------------------------------
extern "C" void kernel_launch(void* const* d_in, const int* in_sizes, int n_in,
                              void* d_out, int out_size, void* d_ws, size_t ws_size,
                              hipStream_t stream)
{
    const float* qx = (const float*)d_in[0];
    const float* kx = (const float*)d_in[1];
    const float* vx = (const float*)d_in[2];
    const float* WQ = (const float*)d_in[3];
    const float* bQ = (const float*)d_in[4];
    const float* WK = (const float*)d_in[5];
    const float* bK = (const float*)d_in[6];
    const float* WV = (const float*)d_in[7];
    const float* bV = (const float*)d_in[8];
    const float* WO = (const float*)d_in[9];
    const float* bO = (const float*)d_in[10];
    float* out = (float*)d_out;

    char* wsb = (char*)d_ws;
    float*          q    = (float*)(wsb);
    float*          k    = (float*)(wsb + (4u  << 20));
    float*          v    = (float*)(wsb + (8u  << 20));
    unsigned short* zh   = (unsigned short*)(wsb + (12u << 20));
    unsigned short* zl   = (unsigned short*)(wsb + (14u << 20));
    unsigned short* wT   = (unsigned short*)(wsb + (16u << 20));
    float*          vsum = (float*)(wsb + (17u << 20));
    float*          part = (float*)(wsb + (17u << 20) + (1u << 16));
    float*          pm   = (float*)(wsb + (17u << 20) + (1u << 18));
    float*          pZ   = pm + 256;
    float*          pzv  = pZ + 256;

    transpose_w_kernel<<<64, 256, 0, stream>>>(WQ, WK, WV, WO, wT);
    gemm_qkv_mfma<<<dim3(128, 12), 64, 0, stream>>>(qx, kx, vx, bQ, bK, bV, wT, q, k, v);
    vsum_part_kernel<<<256, 256, 0, stream>>>(v, part);
    vsum_final_kernel<<<1, 512, 0, stream>>>(part, vsum);
    attn_interior_kernel<<<4092, 256, 0, stream>>>(q, k, v, vsum, zh, zl);
    attn_g1_kernel<<<256, 256, 0, stream>>>(q, k, v, pm, pZ, pzv);
    attn_g2_kernel<<<1, 1024, 0, stream>>>(pm, pZ, pzv, zh, zl);
    gemm_out_mfma<<<dim3(128, 4), 64, 0, stream>>>(zh, zl, wT, bO, out);
}

// Round 4
// 59.377 us; speedup vs baseline: 2.2008x; 1.0554x over previous
//
#include <hip/hip_runtime.h>
#include <hip/hip_bf16.h>

#define B_   2
#define L_   2048
#define C_   256
#define H_   8
#define DK_  32
#define HD_  256
#define RSQRT_DK 0.17677669529663687f  // 1/sqrt(32)

typedef __attribute__((ext_vector_type(8))) short bf16x8;
typedef __attribute__((ext_vector_type(4))) float f32x4;

__device__ __forceinline__ unsigned short f2bf(float x) {
    unsigned int u = __float_as_uint(x);
    u += 0x7fffu + ((u >> 16) & 1u);
    return (unsigned short)(u >> 16);
}
__device__ __forceinline__ float bf2f(unsigned short h) {
    return __uint_as_float((unsigned int)h << 16);
}

// Stage W^T slice (cols n0..n0+63, k 0..255) into LDS as split-bf16 [n][k].
// Row pad 264 shorts: ds_read_b128 B-frags land 2-way bank aliased (free).
__device__ __forceinline__ void stage_wT(
    const float* __restrict__ W, int n0, int tid,
    short (*WTh)[264], short (*WTl)[264])
{
    const int kb = tid >> 4;            // 0..15
    const int c4 = (tid & 15) * 4;      // 0..60
    #pragma unroll
    for (int it = 0; it < 16; ++it) {
        const int kk = kb + it * 16;
        float4 w4 = *reinterpret_cast<const float4*>(&W[(size_t)kk * HD_ + n0 + c4]);
        float xs[4] = {w4.x, w4.y, w4.z, w4.w};
        #pragma unroll
        for (int e = 0; e < 4; ++e) {
            unsigned short h = f2bf(xs[e]);
            WTh[c4 + e][kk] = (short)h;
            WTl[c4 + e][kk] = (short)f2bf(xs[e] - bf2f(h));
        }
    }
}

// ---------------------------------------------------------------------------
// K1: QKV projection, split-bf16 MFMA, weight transpose fused (LDS), and
// deterministic per-block V column-sum partials (for interior softmax).
// Grid (32, 12 = proj*4 + nt), 256 thr = 4 waves; block tile 128x64,
// wave tile 32x64.
// ---------------------------------------------------------------------------
__global__ __launch_bounds__(256) void gemm_qkv_fused(
    const float* __restrict__ qx, const float* __restrict__ kx, const float* __restrict__ vx,
    const float* __restrict__ WQ, const float* __restrict__ bQ,
    const float* __restrict__ WK, const float* __restrict__ bK,
    const float* __restrict__ WV, const float* __restrict__ bV,
    float* __restrict__ q, float* __restrict__ k, float* __restrict__ v,
    float* __restrict__ part)
{
    const int bx = blockIdx.x;          // 0..31
    const int yy = blockIdx.y;          // 0..11
    const int proj = yy >> 2, nt = yy & 3;
    const float* A    = proj == 0 ? qx : (proj == 1 ? kx : vx);
    const float* W    = proj == 0 ? WQ : (proj == 1 ? WK : WV);
    const float* bias = proj == 0 ? bQ : (proj == 1 ? bK : bV);
    float* out        = proj == 0 ? q  : (proj == 1 ? k  : v);
    const int n0 = nt * 64;

    __shared__ short WTh[64][264];
    __shared__ short WTl[64][264];
    __shared__ float red[4][4][16];

    const int tid = threadIdx.x;
    stage_wT(W, n0, tid, WTh, WTl);
    __syncthreads();

    const int w  = tid >> 6;            // wave 0..3
    const int l  = tid & 63;
    const int lm = l & 15, lk8 = (l >> 4) * 8, cr = (l >> 4) * 4;
    const int R  = bx * 128 + w * 32;

    f32x4 acc[2][4];
    #pragma unroll
    for (int mf = 0; mf < 2; ++mf)
        #pragma unroll
        for (int nf = 0; nf < 4; ++nf)
            acc[mf][nf] = (f32x4){0.f, 0.f, 0.f, 0.f};

    float4 Ab[2][4];
    #define LOAD_A(buf, ks)                                                          \
    {                                                                                \
        const float* p0 = &A[(size_t)(R + lm) * C_ + (ks) * 32 + lk8];               \
        const float* p1 = &A[(size_t)(R + 16 + lm) * C_ + (ks) * 32 + lk8];          \
        Ab[buf][0] = *reinterpret_cast<const float4*>(p0);                           \
        Ab[buf][1] = *reinterpret_cast<const float4*>(p0 + 4);                       \
        Ab[buf][2] = *reinterpret_cast<const float4*>(p1);                           \
        Ab[buf][3] = *reinterpret_cast<const float4*>(p1 + 4);                       \
    }
    LOAD_A(0, 0)
    LOAD_A(1, 1)

    #pragma unroll
    for (int ks = 0; ks < 8; ++ks) {
        const int cur = ks & 1;
        bf16x8 ah[2], al[2];
        #pragma unroll
        for (int mf = 0; mf < 2; ++mf) {
            float4 v0 = Ab[cur][mf * 2], v1 = Ab[cur][mf * 2 + 1];
            float xs[8] = {v0.x, v0.y, v0.z, v0.w, v1.x, v1.y, v1.z, v1.w};
            #pragma unroll
            for (int e = 0; e < 8; ++e) {
                unsigned short h = f2bf(xs[e]);
                ah[mf][e] = (short)h;
                al[mf][e] = (short)f2bf(xs[e] - bf2f(h));
            }
        }
        if (ks < 6) LOAD_A(cur, ks + 2)
        bf16x8 Bh[4], Bl[4];
        #pragma unroll
        for (int nf = 0; nf < 4; ++nf) {
            Bh[nf] = *reinterpret_cast<const bf16x8*>(&WTh[nf * 16 + lm][ks * 32 + lk8]);
            Bl[nf] = *reinterpret_cast<const bf16x8*>(&WTl[nf * 16 + lm][ks * 32 + lk8]);
        }
        #pragma unroll
        for (int mf = 0; mf < 2; ++mf)
            #pragma unroll
            for (int nf = 0; nf < 4; ++nf) {
                acc[mf][nf] = __builtin_amdgcn_mfma_f32_16x16x32_bf16(ah[mf], Bh[nf], acc[mf][nf], 0, 0, 0);
                acc[mf][nf] = __builtin_amdgcn_mfma_f32_16x16x32_bf16(ah[mf], Bl[nf], acc[mf][nf], 0, 0, 0);
                acc[mf][nf] = __builtin_amdgcn_mfma_f32_16x16x32_bf16(al[mf], Bh[nf], acc[mf][nf], 0, 0, 0);
            }
    }
    #undef LOAD_A

    // epilogue: bias + scatter to (B,H,L,DK)
    #pragma unroll
    for (int mf = 0; mf < 2; ++mf)
        #pragma unroll
        for (int nf = 0; nf < 4; ++nf) {
            const int col = n0 + nf * 16 + lm;
            const int h = col >> 5, d = col & 31;
            const float bb = bias[col];
            #pragma unroll
            for (int r = 0; r < 4; ++r) {
                const int m = R + mf * 16 + cr + r;
                const int b = m >> 11, lrow = m & (L_ - 1);
                out[((size_t)(b * H_ + h) * L_ + lrow) * DK_ + d] = acc[mf][nf][r] + bb;
            }
        }

    // V column-sum partials (deterministic, per block = 128 rows x 64 cols)
    if (proj == 2) {
        float sl[4];
        #pragma unroll
        for (int nf = 0; nf < 4; ++nf) {
            float s = 0.f;
            #pragma unroll
            for (int mf = 0; mf < 2; ++mf)
                #pragma unroll
                for (int r = 0; r < 4; ++r) s += acc[mf][nf][r];
            s += __shfl_xor(s, 16);
            s += __shfl_xor(s, 32);
            sl[nf] = s;
        }
        if (l < 16) {
            #pragma unroll
            for (int nf = 0; nf < 4; ++nf) red[w][nf][l] = sl[nf];
        }
        __syncthreads();
        if (tid < 64) {
            const int nf = tid >> 4, lmm = tid & 15;
            float tot = red[0][nf][lmm] + red[1][nf][lmm] + red[2][nf][lmm] + red[3][nf][lmm];
            const int col = n0 + nf * 16 + lmm;
            tot += 128.f * bias[col];
            const int h = col >> 5, d = col & 31;
            const int bh = (bx >> 4) * H_ + h;       // block spans one b
            part[((size_t)bh * 32 + d) * 16 + (bx & 15)] = tot;
        }
    }
}

// ---------------------------------------------------------------------------
// K2: all attention rows.  Blocks 0..4091: interior rows (8 rows/block,
// 32 lanes/row).  Blocks 4092..4123: global rows 0 and L-1 (dense softmax).
// Writes z as split-bf16 hi/lo.
// ---------------------------------------------------------------------------
__global__ __launch_bounds__(256) void attn_fused(
    const float* __restrict__ q, const float* __restrict__ k,
    const float* __restrict__ v, const float* __restrict__ part,
    unsigned short* __restrict__ zh, unsigned short* __restrict__ zl)
{
    if (blockIdx.x < 4092) {
        const int tid = threadIdx.x;
        const int d = tid & 31, rg = tid >> 5;
        const long gidx = (long)blockIdx.x * 8 + rg;   // 0..32735
        const int rowsPerBH = L_ - 2;                  // 2046
        const int bh = (int)(gidx / rowsPerBH);
        const int i = 1 + (int)(gidx % rowsPerBH);

        const float* qb = q + (size_t)bh * L_ * DK_;
        const float* kb = k + (size_t)bh * L_ * DK_;
        const float* vb = v + (size_t)bh * L_ * DK_;

        const float qd = qb[i * DK_ + d];

        int cols[5] = {0, i - 1, i, i + 1, L_ - 1};
        bool valid[5] = {true, i != 1, true, i != L_ - 2, true};

        float s[5];
        #pragma unroll
        for (int jj = 0; jj < 5; ++jj) {
            float p = qd * kb[cols[jj] * DK_ + d];
            #pragma unroll
            for (int off = 16; off; off >>= 1) p += __shfl_xor(p, off, 32);
            s[jj] = p * RSQRT_DK;
        }

        float m = 0.f;   // zero-score filler entries participate in row max
        int ns = 0;
        #pragma unroll
        for (int jj = 0; jj < 5; ++jj) {
            if (valid[jj]) { m = fmaxf(m, s[jj]); ns++; }
        }

        float e[5], sume = 0.f;
        #pragma unroll
        for (int jj = 0; jj < 5; ++jj) {
            e[jj] = valid[jj] ? __expf(s[jj] - m) : 0.f;
            sume += e[jj];
        }
        const float e0 = __expf(-m);
        const float Z = sume + (float)(L_ - ns) * e0;

        // inline vsum: 16 deterministic partials from K1
        const float4* pp = reinterpret_cast<const float4*>(&part[((size_t)bh * 32 + d) * 16]);
        float4 pa = pp[0], pb = pp[1], pc = pp[2], pd = pp[3];
        const float vs = pa.x + pa.y + pa.z + pa.w + pb.x + pb.y + pb.z + pb.w
                       + pc.x + pc.y + pc.z + pc.w + pd.x + pd.y + pd.z + pd.w;

        float zd = 0.f, vp = 0.f;
        #pragma unroll
        for (int jj = 0; jj < 5; ++jj) {
            float vd = vb[cols[jj] * DK_ + d];
            zd += e[jj] * vd;
            vp += valid[jj] ? vd : 0.f;
        }
        zd += e0 * (vs - vp);
        zd /= Z;

        const int b = bh >> 3, h = bh & 7;
        const size_t o = (size_t)(b * L_ + i) * HD_ + h * DK_ + d;
        const unsigned short hb = f2bf(zd);
        zh[o] = hb;
        zl[o] = f2bf(zd - bf2f(hb));
    } else {
        const int blk2 = blockIdx.x - 4092;            // 0..31
        const int bh = blk2 >> 1;
        const int r = (blk2 & 1) ? (L_ - 1) : 0;
        const float* qb = q + (size_t)bh * L_ * DK_;
        const float* kb = k + (size_t)bh * L_ * DK_;
        const float* vb = v + (size_t)bh * L_ * DK_;

        __shared__ float sc[L_];
        __shared__ float qs[DK_];
        __shared__ float redm[4], reds2[4];
        __shared__ float pz[8][32];

        const int t = threadIdx.x;
        if (t < DK_) qs[t] = qb[(size_t)r * DK_ + t];
        __syncthreads();

        float lmax = -1e30f;
        #pragma unroll
        for (int rep = 0; rep < 8; ++rep) {
            const int j = t + rep * 256;
            const float4* kr = reinterpret_cast<const float4*>(&kb[(size_t)j * DK_]);
            float p = 0.f;
            #pragma unroll
            for (int u = 0; u < 8; ++u) {
                float4 kv = kr[u];
                p += qs[u * 4 + 0] * kv.x + qs[u * 4 + 1] * kv.y
                   + qs[u * 4 + 2] * kv.z + qs[u * 4 + 3] * kv.w;
            }
            p *= RSQRT_DK;
            sc[j] = p;
            lmax = fmaxf(lmax, p);
        }
        #pragma unroll
        for (int off = 32; off; off >>= 1) lmax = fmaxf(lmax, __shfl_xor(lmax, off, 64));
        if ((t & 63) == 0) redm[t >> 6] = lmax;
        __syncthreads();
        const float m = fmaxf(fmaxf(redm[0], redm[1]), fmaxf(redm[2], redm[3]));

        float lsum = 0.f;
        #pragma unroll
        for (int rep = 0; rep < 8; ++rep) {
            const int j = t + rep * 256;
            const float e = __expf(sc[j] - m);
            sc[j] = e;
            lsum += e;
        }
        #pragma unroll
        for (int off = 32; off; off >>= 1) lsum += __shfl_xor(lsum, off, 64);
        if ((t & 63) == 0) reds2[t >> 6] = lsum;
        __syncthreads();
        const float Z = reds2[0] + reds2[1] + reds2[2] + reds2[3];

        const int d = t & 31, g = t >> 5;
        float acc = 0.f;
        #pragma unroll 8
        for (int j = g * 256; j < g * 256 + 256; ++j)
            acc += sc[j] * vb[(size_t)j * DK_ + d];
        pz[g][d] = acc;
        __syncthreads();
        if (g == 0) {
            float ss = 0.f;
            #pragma unroll
            for (int gg = 0; gg < 8; ++gg) ss += pz[gg][d];
            const float zd = ss / Z;
            const int b = bh >> 3, h = bh & 7;
            const size_t o = (size_t)(b * L_ + r) * HD_ + h * DK_ + d;
            const unsigned short hb = f2bf(zd);
            zh[o] = hb;
            zl[o] = f2bf(zd - bf2f(hb));
        }
    }
}

// ---------------------------------------------------------------------------
// K3: out = z @ WO + bO via split-bf16 MFMA, WO transpose fused (LDS).
// Grid (64, 4), 256 thr = 4 waves; block tile 64x64, wave tile 16x64.
// ---------------------------------------------------------------------------
__global__ __launch_bounds__(256) void gemm_out_fused(
    const unsigned short* __restrict__ zh, const unsigned short* __restrict__ zl,
    const float* __restrict__ WO, const float* __restrict__ bO,
    float* __restrict__ out)
{
    const int bx = blockIdx.x;          // 0..63
    const int nt = blockIdx.y;          // 0..3
    const int n0 = nt * 64;

    __shared__ short WTh[64][264];
    __shared__ short WTl[64][264];

    const int tid = threadIdx.x;
    stage_wT(WO, n0, tid, WTh, WTl);
    __syncthreads();

    const int w  = tid >> 6;
    const int l  = tid & 63;
    const int lm = l & 15, lk8 = (l >> 4) * 8, cr = (l >> 4) * 4;
    const int R  = bx * 64 + w * 16;

    f32x4 acc[4];
    #pragma unroll
    for (int nf = 0; nf < 4; ++nf) acc[nf] = (f32x4){0.f, 0.f, 0.f, 0.f};

    bf16x8 Ah[2], Al[2];
    #define LOAD_Z(buf, ks)                                                          \
    {                                                                                \
        const size_t o = (size_t)(R + lm) * HD_ + (ks) * 32 + lk8;                   \
        Ah[buf] = *reinterpret_cast<const bf16x8*>(&zh[o]);                          \
        Al[buf] = *reinterpret_cast<const bf16x8*>(&zl[o]);                          \
    }
    LOAD_Z(0, 0)
    LOAD_Z(1, 1)

    #pragma unroll
    for (int ks = 0; ks < 8; ++ks) {
        const int cur = ks & 1;
        const bf16x8 a_h = Ah[cur], a_l = Al[cur];
        if (ks < 6) LOAD_Z(cur, ks + 2)
        #pragma unroll
        for (int nf = 0; nf < 4; ++nf) {
            const bf16x8 b_h = *reinterpret_cast<const bf16x8*>(&WTh[nf * 16 + lm][ks * 32 + lk8]);
            const bf16x8 b_l = *reinterpret_cast<const bf16x8*>(&WTl[nf * 16 + lm][ks * 32 + lk8]);
            acc[nf] = __builtin_amdgcn_mfma_f32_16x16x32_bf16(a_h, b_h, acc[nf], 0, 0, 0);
            acc[nf] = __builtin_amdgcn_mfma_f32_16x16x32_bf16(a_h, b_l, acc[nf], 0, 0, 0);
            acc[nf] = __builtin_amdgcn_mfma_f32_16x16x32_bf16(a_l, b_h, acc[nf], 0, 0, 0);
        }
    }
    #undef LOAD_Z

    #pragma unroll
    for (int nf = 0; nf < 4; ++nf) {
        const int col = n0 + nf * 16 + lm;
        const float bb = bO[col];
        #pragma unroll
        for (int r = 0; r < 4; ++r) {
            const int m = R + cr + r;
            out[(size_t)m * HD_ + col] = acc[nf][r] + bb;
        }
    }
}

// ---------------------------------------------------------------------------
extern "C" void kernel_launch(void* const* d_in, const int* in_sizes, int n_in,
                              void* d_out, int out_size, void* d_ws, size_t ws_size,
                              hipStream_t stream)
{
    const float* qx = (const float*)d_in[0];
    const float* kx = (const float*)d_in[1];
    const float* vx = (const float*)d_in[2];
    const float* WQ = (const float*)d_in[3];
    const float* bQ = (const float*)d_in[4];
    const float* WK = (const float*)d_in[5];
    const float* bK = (const float*)d_in[6];
    const float* WV = (const float*)d_in[7];
    const float* bV = (const float*)d_in[8];
    const float* WO = (const float*)d_in[9];
    const float* bO = (const float*)d_in[10];
    float* out = (float*)d_out;

    char* wsb = (char*)d_ws;
    float*          q    = (float*)(wsb);
    float*          k    = (float*)(wsb + (4u  << 20));
    float*          v    = (float*)(wsb + (8u  << 20));
    unsigned short* zh   = (unsigned short*)(wsb + (12u << 20));
    unsigned short* zl   = (unsigned short*)(wsb + (14u << 20));
    float*          part = (float*)(wsb + (16u << 20));   // 16 bh x 32 d x 16 = 32 KB

    gemm_qkv_fused<<<dim3(32, 12), 256, 0, stream>>>(qx, kx, vx, WQ, bQ, WK, bK, WV, bV, q, k, v, part);
    attn_fused<<<4124, 256, 0, stream>>>(q, k, v, part, zh, zl);
    gemm_out_fused<<<dim3(64, 4), 256, 0, stream>>>(zh, zl, WO, bO, out);
}

// Round 5
// 47.547 us; speedup vs baseline: 2.7483x; 1.2488x over previous
//
#include <hip/hip_runtime.h>
#include <hip/hip_bf16.h>

#define B_   2
#define L_   2048
#define C_   256
#define H_   8
#define DK_  32
#define HD_  256
#define RSQRT_DK 0.17677669529663687f  // 1/sqrt(32)

typedef __attribute__((ext_vector_type(8))) short bf16x8;
typedef __attribute__((ext_vector_type(4))) float f32x4;

__device__ __forceinline__ unsigned short f2bf(float x) {
    unsigned int u = __float_as_uint(x);
    u += 0x7fffu + ((u >> 16) & 1u);
    return (unsigned short)(u >> 16);
}
__device__ __forceinline__ float bf2f(unsigned short h) {
    return __uint_as_float((unsigned int)h << 16);
}

// Stage W^T slice (cols n0..n0+63, k 0..255) into LDS as split-bf16 [n][k].
// Row pad 264 shorts: ds_read_b128 B-frags land 2-way bank aliased (free).
__device__ __forceinline__ void stage_wT(
    const float* __restrict__ W, int n0, int tid,
    short (*WTh)[264], short (*WTl)[264])
{
    const int kb = tid >> 4;            // 0..15
    const int c4 = (tid & 15) * 4;      // 0..60
    #pragma unroll
    for (int it = 0; it < 16; ++it) {
        const int kk = kb + it * 16;
        float4 w4 = *reinterpret_cast<const float4*>(&W[(size_t)kk * HD_ + n0 + c4]);
        float xs[4] = {w4.x, w4.y, w4.z, w4.w};
        #pragma unroll
        for (int e = 0; e < 4; ++e) {
            unsigned short h = f2bf(xs[e]);
            WTh[c4 + e][kk] = (short)h;
            WTl[c4 + e][kk] = (short)f2bf(xs[e] - bf2f(h));
        }
    }
}

// ---------------------------------------------------------------------------
// K1: QKV projection, split-bf16 MFMA, weight transpose fused (LDS), and
// deterministic per-block V column-sum partials (for interior softmax).
// (unchanged from round 4)
// ---------------------------------------------------------------------------
__global__ __launch_bounds__(256) void gemm_qkv_fused(
    const float* __restrict__ qx, const float* __restrict__ kx, const float* __restrict__ vx,
    const float* __restrict__ WQ, const float* __restrict__ bQ,
    const float* __restrict__ WK, const float* __restrict__ bK,
    const float* __restrict__ WV, const float* __restrict__ bV,
    float* __restrict__ q, float* __restrict__ k, float* __restrict__ v,
    float* __restrict__ part)
{
    const int bx = blockIdx.x;          // 0..31
    const int yy = blockIdx.y;          // 0..11
    const int proj = yy >> 2, nt = yy & 3;
    const float* A    = proj == 0 ? qx : (proj == 1 ? kx : vx);
    const float* W    = proj == 0 ? WQ : (proj == 1 ? WK : WV);
    const float* bias = proj == 0 ? bQ : (proj == 1 ? bK : bV);
    float* out        = proj == 0 ? q  : (proj == 1 ? k  : v);
    const int n0 = nt * 64;

    __shared__ short WTh[64][264];
    __shared__ short WTl[64][264];
    __shared__ float red[4][4][16];

    const int tid = threadIdx.x;
    stage_wT(W, n0, tid, WTh, WTl);
    __syncthreads();

    const int w  = tid >> 6;            // wave 0..3
    const int l  = tid & 63;
    const int lm = l & 15, lk8 = (l >> 4) * 8, cr = (l >> 4) * 4;
    const int R  = bx * 128 + w * 32;

    f32x4 acc[2][4];
    #pragma unroll
    for (int mf = 0; mf < 2; ++mf)
        #pragma unroll
        for (int nf = 0; nf < 4; ++nf)
            acc[mf][nf] = (f32x4){0.f, 0.f, 0.f, 0.f};

    float4 Ab[2][4];
    #define LOAD_A(buf, ks)                                                          \
    {                                                                                \
        const float* p0 = &A[(size_t)(R + lm) * C_ + (ks) * 32 + lk8];               \
        const float* p1 = &A[(size_t)(R + 16 + lm) * C_ + (ks) * 32 + lk8];          \
        Ab[buf][0] = *reinterpret_cast<const float4*>(p0);                           \
        Ab[buf][1] = *reinterpret_cast<const float4*>(p0 + 4);                       \
        Ab[buf][2] = *reinterpret_cast<const float4*>(p1);                           \
        Ab[buf][3] = *reinterpret_cast<const float4*>(p1 + 4);                       \
    }
    LOAD_A(0, 0)
    LOAD_A(1, 1)

    #pragma unroll
    for (int ks = 0; ks < 8; ++ks) {
        const int cur = ks & 1;
        bf16x8 ah[2], al[2];
        #pragma unroll
        for (int mf = 0; mf < 2; ++mf) {
            float4 v0 = Ab[cur][mf * 2], v1 = Ab[cur][mf * 2 + 1];
            float xs[8] = {v0.x, v0.y, v0.z, v0.w, v1.x, v1.y, v1.z, v1.w};
            #pragma unroll
            for (int e = 0; e < 8; ++e) {
                unsigned short h = f2bf(xs[e]);
                ah[mf][e] = (short)h;
                al[mf][e] = (short)f2bf(xs[e] - bf2f(h));
            }
        }
        if (ks < 6) LOAD_A(cur, ks + 2)
        bf16x8 Bh[4], Bl[4];
        #pragma unroll
        for (int nf = 0; nf < 4; ++nf) {
            Bh[nf] = *reinterpret_cast<const bf16x8*>(&WTh[nf * 16 + lm][ks * 32 + lk8]);
            Bl[nf] = *reinterpret_cast<const bf16x8*>(&WTl[nf * 16 + lm][ks * 32 + lk8]);
        }
        #pragma unroll
        for (int mf = 0; mf < 2; ++mf)
            #pragma unroll
            for (int nf = 0; nf < 4; ++nf) {
                acc[mf][nf] = __builtin_amdgcn_mfma_f32_16x16x32_bf16(ah[mf], Bh[nf], acc[mf][nf], 0, 0, 0);
                acc[mf][nf] = __builtin_amdgcn_mfma_f32_16x16x32_bf16(ah[mf], Bl[nf], acc[mf][nf], 0, 0, 0);
                acc[mf][nf] = __builtin_amdgcn_mfma_f32_16x16x32_bf16(al[mf], Bh[nf], acc[mf][nf], 0, 0, 0);
            }
    }
    #undef LOAD_A

    // epilogue: bias + scatter to (B,H,L,DK)
    #pragma unroll
    for (int mf = 0; mf < 2; ++mf)
        #pragma unroll
        for (int nf = 0; nf < 4; ++nf) {
            const int col = n0 + nf * 16 + lm;
            const int h = col >> 5, d = col & 31;
            const float bb = bias[col];
            #pragma unroll
            for (int r = 0; r < 4; ++r) {
                const int m = R + mf * 16 + cr + r;
                const int b = m >> 11, lrow = m & (L_ - 1);
                out[((size_t)(b * H_ + h) * L_ + lrow) * DK_ + d] = acc[mf][nf][r] + bb;
            }
        }

    // V column-sum partials (deterministic, per block = 128 rows x 64 cols)
    if (proj == 2) {
        float sl[4];
        #pragma unroll
        for (int nf = 0; nf < 4; ++nf) {
            float s = 0.f;
            #pragma unroll
            for (int mf = 0; mf < 2; ++mf)
                #pragma unroll
                for (int r = 0; r < 4; ++r) s += acc[mf][nf][r];
            s += __shfl_xor(s, 16);
            s += __shfl_xor(s, 32);
            sl[nf] = s;
        }
        if (l < 16) {
            #pragma unroll
            for (int nf = 0; nf < 4; ++nf) red[w][nf][l] = sl[nf];
        }
        __syncthreads();
        if (tid < 64) {
            const int nf = tid >> 4, lmm = tid & 15;
            float tot = red[0][nf][lmm] + red[1][nf][lmm] + red[2][nf][lmm] + red[3][nf][lmm];
            const int col = n0 + nf * 16 + lmm;
            tot += 128.f * bias[col];
            const int h = col >> 5, d = col & 31;
            const int bh = (bx >> 4) * H_ + h;       // block spans one b
            part[((size_t)bh * 32 + d) * 16 + (bx & 15)] = tot;
        }
    }
}

// ---------------------------------------------------------------------------
// K2: attention.
//  Blocks 0..255   : interior rows, ONE ROW PER LANE (bh = blk>>4, 128-row
//                    chunk = blk&15).  K/V/Q staged in LDS with XOR-quad
//                    swizzle (16B aligned, conflict-free).
//  Blocks 256..767 : global-row partials (bh, row-pair, 128-col chunk).
// 128 threads (2 waves) per block.
// ---------------------------------------------------------------------------
#define NSLOT 392            // 132 K + 132 V + 128 Q
#define KOFF  0
#define VOFF  132
#define QOFF  264

__global__ __launch_bounds__(128) void attn_main(
    const float* __restrict__ q, const float* __restrict__ k,
    const float* __restrict__ v, const float* __restrict__ part,
    float* __restrict__ pm, float* __restrict__ pZ, float* __restrict__ pzv,
    unsigned short* __restrict__ zh, unsigned short* __restrict__ zl)
{
    __shared__ float Sf[NSLOT * 32 + 32];
    float* vs_sh = &Sf[NSLOT * 32];

    // logical (slot, quad, elem) -> phys dword: slot*32 + ((quad ^ (slot&7))<<2) + elem
    #define LDS_F4(slot, u2) (*reinterpret_cast<const float4*>(&Sf[((slot) << 5) + (((u2) ^ ((slot) & 7)) << 2)]))

    const int blk = blockIdx.x;
    const int t = threadIdx.x;

    if (blk < 256) {
        // ----------------- interior rows, per-lane -----------------
        const int bh = blk >> 4, c = blk & 15;
        const int base = c * 128;                   // slot s (<130) = row base+s
        const float* qb = q + (size_t)bh * L_ * DK_;
        const float* kb = k + (size_t)bh * L_ * DK_;
        const float* vb = v + (size_t)bh * L_ * DK_;

        // stage K(132 slots) V(132) Q(128) = 3136 float4 units
        for (int u = t; u < NSLOT * 8; u += 128) {
            const int slot = u >> 3, quad = u & 7;
            int row; const float* src;
            if (slot < VOFF) {
                const int s = slot;
                row = (s < 130) ? min(base + s, L_ - 1) : ((s == 130) ? 0 : L_ - 1);
                src = kb;
            } else if (slot < QOFF) {
                const int s = slot - VOFF;
                row = (s < 130) ? min(base + s, L_ - 1) : ((s == 130) ? 0 : L_ - 1);
                src = vb;
            } else {
                row = min(base + 1 + (slot - QOFF), L_ - 1);
                src = qb;
            }
            float4 w4 = *reinterpret_cast<const float4*>(&src[(size_t)row * DK_ + quad * 4]);
            float* dst = &Sf[(slot << 5) + ((quad ^ (slot & 7)) << 2)];
            dst[0] = w4.x; dst[1] = w4.y; dst[2] = w4.z; dst[3] = w4.w;
        }
        if (t < 32) {
            const float4* pp = reinterpret_cast<const float4*>(&part[((size_t)bh * 32 + t) * 16]);
            float4 pa = pp[0], pb = pp[1], pc = pp[2], pd = pp[3];
            vs_sh[t] = pa.x + pa.y + pa.z + pa.w + pb.x + pb.y + pb.z + pb.w
                     + pc.x + pc.y + pc.z + pc.w + pd.x + pd.y + pd.z + pd.w;
        }
        __syncthreads();

        const int i = base + 1 + t;
        if (i <= L_ - 2) {
            float qr[32];
            {
                const int qs = QOFF + t;
                #pragma unroll
                for (int u2 = 0; u2 < 8; ++u2) {
                    float4 x = LDS_F4(qs, u2);
                    qr[u2 * 4 + 0] = x.x; qr[u2 * 4 + 1] = x.y;
                    qr[u2 * 4 + 2] = x.z; qr[u2 * 4 + 3] = x.w;
                }
            }
            const int ks_[5] = {130, t, t + 1, t + 2, 131};   // cols 0, i-1, i, i+1, L-1
            float sv[5];
            #pragma unroll
            for (int jj = 0; jj < 5; ++jj) {
                const int s = ks_[jj];
                float p = 0.f;
                #pragma unroll
                for (int u2 = 0; u2 < 8; ++u2) {
                    float4 kv = LDS_F4(s, u2);
                    p += qr[u2 * 4 + 0] * kv.x + qr[u2 * 4 + 1] * kv.y
                       + qr[u2 * 4 + 2] * kv.z + qr[u2 * 4 + 3] * kv.w;
                }
                sv[jj] = p * RSQRT_DK;
            }
            const bool v1 = (i != 1), v3 = (i != L_ - 2);
            float m = fmaxf(0.f, sv[0]);                 // zero fillers join the max
            m = fmaxf(m, sv[2]); m = fmaxf(m, sv[4]);
            if (v1) m = fmaxf(m, sv[1]);
            if (v3) m = fmaxf(m, sv[3]);
            float e[5];
            e[0] = __expf(sv[0] - m);
            e[1] = v1 ? __expf(sv[1] - m) : 0.f;
            e[2] = __expf(sv[2] - m);
            e[3] = v3 ? __expf(sv[3] - m) : 0.f;
            e[4] = __expf(sv[4] - m);
            const int ns = 3 + (int)v1 + (int)v3;
            const float e0 = __expf(-m);
            const float Z = e[0] + e[1] + e[2] + e[3] + e[4] + (float)(L_ - ns) * e0;
            const float rZ = 1.f / Z;
            const float f1 = v1 ? 1.f : 0.f, f3 = v3 ? 1.f : 0.f;

            bf16x8 zh8[4], zl8[4];
            #pragma unroll
            for (int u2 = 0; u2 < 8; ++u2) {
                float4 x0 = LDS_F4(VOFF + 130,   u2);
                float4 x1 = LDS_F4(VOFF + t,     u2);
                float4 x2 = LDS_F4(VOFF + t + 1, u2);
                float4 x3 = LDS_F4(VOFF + t + 2, u2);
                float4 x4 = LDS_F4(VOFF + 131,   u2);
                float a0[4] = {x0.x, x0.y, x0.z, x0.w};
                float a1[4] = {x1.x, x1.y, x1.z, x1.w};
                float a2[4] = {x2.x, x2.y, x2.z, x2.w};
                float a3[4] = {x3.x, x3.y, x3.z, x3.w};
                float a4[4] = {x4.x, x4.y, x4.z, x4.w};
                #pragma unroll
                for (int e2 = 0; e2 < 4; ++e2) {
                    const int d = u2 * 4 + e2;
                    const float num = e[0] * a0[e2] + e[1] * a1[e2] + e[2] * a2[e2]
                                    + e[3] * a3[e2] + e[4] * a4[e2];
                    const float vp = a0[e2] + f1 * a1[e2] + a2[e2] + f3 * a3[e2] + a4[e2];
                    const float zd = (num + e0 * (vs_sh[d] - vp)) * rZ;
                    const unsigned short hb = f2bf(zd);
                    zh8[d >> 3][d & 7] = (short)hb;
                    zl8[d >> 3][d & 7] = (short)f2bf(zd - bf2f(hb));
                }
            }
            const int b = bh >> 3, h = bh & 7;
            const size_t o = (size_t)(b * L_ + i) * HD_ + h * DK_;
            #pragma unroll
            for (int u4 = 0; u4 < 4; ++u4) {
                *reinterpret_cast<bf16x8*>(&zh[o + u4 * 8]) = zh8[u4];
                *reinterpret_cast<bf16x8*>(&zl[o + u4 * 8]) = zl8[u4];
            }
        }
    } else {
        // ----------------- global-row partials -----------------
        const int blk2 = blk - 256;                 // 0..511
        const int bh = blk2 >> 5;
        const int pair = (blk2 >> 4) & 1;
        const int chunk = blk2 & 15;
        const int r = pair ? (L_ - 1) : 0;
        const int j0 = chunk * 128;
        const float* qb = q + (size_t)bh * L_ * DK_;
        const float* kb = k + (size_t)bh * L_ * DK_;
        const float* vb = v + (size_t)bh * L_ * DK_;

        float* qs  = Sf;          // 32
        float* sc  = Sf + 32;     // 128
        float* red = Sf + 160;    // 4
        float* pzs = Sf + 192;    // 128

        if (t < 32) qs[t] = qb[(size_t)r * DK_ + t];
        __syncthreads();

        const int j = j0 + t;
        const float4* kr = reinterpret_cast<const float4*>(&kb[(size_t)j * DK_]);
        float p = 0.f;
        #pragma unroll
        for (int u = 0; u < 8; ++u) {
            float4 kv = kr[u];
            p += qs[u * 4 + 0] * kv.x + qs[u * 4 + 1] * kv.y
               + qs[u * 4 + 2] * kv.z + qs[u * 4 + 3] * kv.w;
        }
        p *= RSQRT_DK;

        float lm = p;
        #pragma unroll
        for (int off = 32; off; off >>= 1) lm = fmaxf(lm, __shfl_xor(lm, off, 64));
        if ((t & 63) == 0) red[t >> 6] = lm;
        __syncthreads();
        const float m = fmaxf(red[0], red[1]);

        const float e = __expf(p - m);
        sc[t] = e;
        float ls = e;
        #pragma unroll
        for (int off = 32; off; off >>= 1) ls += __shfl_xor(ls, off, 64);
        if ((t & 63) == 0) red[2 + (t >> 6)] = ls;
        __syncthreads();
        const float Zc = red[2] + red[3];

        const int d = t & 31, g = t >> 5;
        float acc = 0.f;
        #pragma unroll 4
        for (int jj = 0; jj < 32; ++jj)
            acc += sc[g * 32 + jj] * vb[(size_t)(j0 + g * 32 + jj) * DK_ + d];
        pzs[g * 32 + d] = acc;
        __syncthreads();
        if (g == 0) {
            const float s2 = pzs[d] + pzs[32 + d] + pzs[64 + d] + pzs[96 + d];
            pzv[(size_t)blk2 * 32 + d] = s2;
        }
        if (t == 0) { pm[blk2] = m; pZ[blk2] = Zc; }
    }
    #undef LDS_F4
}

// ---------------------------------------------------------------------------
// K2b: combine 16 chunks per global row; write z hi/lo.  1 block.
// ---------------------------------------------------------------------------
__global__ __launch_bounds__(1024) void attn_g2_kernel(
    const float* __restrict__ pm, const float* __restrict__ pZ,
    const float* __restrict__ pzv,
    unsigned short* __restrict__ zh, unsigned short* __restrict__ zl)
{
    const int t = threadIdx.x;           // 0..1023
    const int rowIdx = t >> 5;           // 0..31 (= bh*2 + pair)
    const int d = t & 31;
    const int bh = rowIdx >> 1, pair = rowIdx & 1;
    const int base = rowIdx * 16;

    float m = -1e30f;
    #pragma unroll
    for (int c = 0; c < 16; ++c) m = fmaxf(m, pm[base + c]);
    float Z = 0.f, zd = 0.f;
    #pragma unroll
    for (int c = 0; c < 16; ++c) {
        const float w = __expf(pm[base + c] - m);
        Z  += pZ[base + c] * w;
        zd += pzv[(size_t)(base + c) * 32 + d] * w;
    }
    zd /= Z;

    const int r = pair ? (L_ - 1) : 0;
    const int b = bh >> 3, h = bh & 7;
    const size_t o = (size_t)(b * L_ + r) * HD_ + h * DK_ + d;
    const unsigned short hb = f2bf(zd);
    zh[o] = hb;
    zl[o] = f2bf(zd - bf2f(hb));
}

// ---------------------------------------------------------------------------
// K3: out = z @ WO + bO via split-bf16 MFMA, WO transpose fused (LDS).
// (unchanged from round 4)
// ---------------------------------------------------------------------------
__global__ __launch_bounds__(256) void gemm_out_fused(
    const unsigned short* __restrict__ zh, const unsigned short* __restrict__ zl,
    const float* __restrict__ WO, const float* __restrict__ bO,
    float* __restrict__ out)
{
    const int bx = blockIdx.x;          // 0..63
    const int nt = blockIdx.y;          // 0..3
    const int n0 = nt * 64;

    __shared__ short WTh[64][264];
    __shared__ short WTl[64][264];

    const int tid = threadIdx.x;
    stage_wT(WO, n0, tid, WTh, WTl);
    __syncthreads();

    const int w  = tid >> 6;
    const int l  = tid & 63;
    const int lm = l & 15, lk8 = (l >> 4) * 8, cr = (l >> 4) * 4;
    const int R  = bx * 64 + w * 16;

    f32x4 acc[4];
    #pragma unroll
    for (int nf = 0; nf < 4; ++nf) acc[nf] = (f32x4){0.f, 0.f, 0.f, 0.f};

    bf16x8 Ah[2], Al[2];
    #define LOAD_Z(buf, ks)                                                          \
    {                                                                                \
        const size_t o = (size_t)(R + lm) * HD_ + (ks) * 32 + lk8;                   \
        Ah[buf] = *reinterpret_cast<const bf16x8*>(&zh[o]);                          \
        Al[buf] = *reinterpret_cast<const bf16x8*>(&zl[o]);                          \
    }
    LOAD_Z(0, 0)
    LOAD_Z(1, 1)

    #pragma unroll
    for (int ks = 0; ks < 8; ++ks) {
        const int cur = ks & 1;
        const bf16x8 a_h = Ah[cur], a_l = Al[cur];
        if (ks < 6) LOAD_Z(cur, ks + 2)
        #pragma unroll
        for (int nf = 0; nf < 4; ++nf) {
            const bf16x8 b_h = *reinterpret_cast<const bf16x8*>(&WTh[nf * 16 + lm][ks * 32 + lk8]);
            const bf16x8 b_l = *reinterpret_cast<const bf16x8*>(&WTl[nf * 16 + lm][ks * 32 + lk8]);
            acc[nf] = __builtin_amdgcn_mfma_f32_16x16x32_bf16(a_h, b_h, acc[nf], 0, 0, 0);
            acc[nf] = __builtin_amdgcn_mfma_f32_16x16x32_bf16(a_h, b_l, acc[nf], 0, 0, 0);
            acc[nf] = __builtin_amdgcn_mfma_f32_16x16x32_bf16(a_l, b_h, acc[nf], 0, 0, 0);
        }
    }
    #undef LOAD_Z

    #pragma unroll
    for (int nf = 0; nf < 4; ++nf) {
        const int col = n0 + nf * 16 + lm;
        const float bb = bO[col];
        #pragma unroll
        for (int r = 0; r < 4; ++r) {
            const int m = R + cr + r;
            out[(size_t)m * HD_ + col] = acc[nf][r] + bb;
        }
    }
}

// ---------------------------------------------------------------------------
extern "C" void kernel_launch(void* const* d_in, const int* in_sizes, int n_in,
                              void* d_out, int out_size, void* d_ws, size_t ws_size,
                              hipStream_t stream)
{
    const float* qx = (const float*)d_in[0];
    const float* kx = (const float*)d_in[1];
    const float* vx = (const float*)d_in[2];
    const float* WQ = (const float*)d_in[3];
    const float* bQ = (const float*)d_in[4];
    const float* WK = (const float*)d_in[5];
    const float* bK = (const float*)d_in[6];
    const float* WV = (const float*)d_in[7];
    const float* bV = (const float*)d_in[8];
    const float* WO = (const float*)d_in[9];
    const float* bO = (const float*)d_in[10];
    float* out = (float*)d_out;

    char* wsb = (char*)d_ws;
    float*          q    = (float*)(wsb);
    float*          k    = (float*)(wsb + (4u  << 20));
    float*          v    = (float*)(wsb + (8u  << 20));
    unsigned short* zh   = (unsigned short*)(wsb + (12u << 20));
    unsigned short* zl   = (unsigned short*)(wsb + (14u << 20));
    float*          part = (float*)(wsb + (16u << 20));             // 32 KB
    float*          pm   = (float*)(wsb + (16u << 20) + (1u << 16)); // 512 f
    float*          pZ   = pm + 512;
    float*          pzv  = pm + 1024;                                // 16384 f

    gemm_qkv_fused<<<dim3(32, 12), 256, 0, stream>>>(qx, kx, vx, WQ, bQ, WK, bK, WV, bV, q, k, v, part);
    attn_main<<<768, 128, 0, stream>>>(q, k, v, part, pm, pZ, pzv, zh, zl);
    attn_g2_kernel<<<1, 1024, 0, stream>>>(pm, pZ, pzv, zh, zl);
    gemm_out_fused<<<dim3(64, 4), 256, 0, stream>>>(zh, zl, WO, bO, out);
}